// Round 8
// baseline (1338.967 us; speedup 1.0000x reference)
//
#include <hip/hip_runtime.h>
#include <hip/hip_bf16.h>

#define DM_   1024
#define NLAY  8
#define NST   16
#define EE    2048
#define E2    4096
#define RNK   64
#define SEQ   1024
#define NXD   96
#define VOC   256
#define EPS_  1e-5f
#define NCH   32
#define CLEN  32

typedef __attribute__((ext_vector_type(8))) short bf16x8;
typedef __attribute__((ext_vector_type(8))) unsigned short u16x8;
typedef __attribute__((ext_vector_type(4))) float f32x4;
typedef __hip_bfloat16 bf16;

__device__ __forceinline__ float sigmoidf_(float x){ return 1.f/(1.f+__expf(-x)); }
__device__ __forceinline__ float softplusf_(float x){ return (x>15.f)?x:log1pf(__expf(x)); }
__device__ __forceinline__ short f2bf_s(float x){
  union { bf16 b; short s; } cv; cv.b = __float2bfloat16(x); return cv.s;
}

__device__ __forceinline__ void gld_lds16(const short* g, short* lds_uniform){
  __builtin_amdgcn_global_load_lds(
      (const __attribute__((address_space(1))) unsigned int*)(const void*)g,
      (__attribute__((address_space(3))) unsigned int*)(void*)lds_uniform,
      16, 0, 0);
}

// ---------------- prep: weight transposes f32 (R,C) -> bf16 (C,R) ----------------
// 64x32 tiles; bf16 stored transposed in LDS; 16B coalesced output stores.
// Requires R % 64 == 0, C % 32 == 0 (holds for all five tensors).
__device__ void t_job(const float* in, bf16* out, int R, int C, int L,
                      short* tileT /*32 x 68 shorts*/, int gdim){
  int tC = C >> 5, tR = R >> 6;
  int per = tC * tR, total = per * L;
  int tid = threadIdx.x;
  int cc = tid >> 3, sg = tid & 7;   // write-back mapping
  for (int it = blockIdx.x; it < total; it += gdim){
    int l = it / per, rem = it - l*per;
    int tc = rem % tC, tr = rem / tC;
    const float* inp = in + (size_t)l*R*C;
    bf16* outp = out + (size_t)l*R*C;
    int c0 = tc*32, r0 = tr*64;
    __syncthreads();
#pragma unroll
    for (int jr = 0; jr < 2; jr++){
      int idx = tid + jr*256;
      int row = idx >> 3, fc = idx & 7;
      float4 v = *(const float4*)(inp + (size_t)(r0+row)*C + c0 + fc*4);
      tileT[(fc*4+0)*68 + row] = f2bf_s(v.x);
      tileT[(fc*4+1)*68 + row] = f2bf_s(v.y);
      tileT[(fc*4+2)*68 + row] = f2bf_s(v.z);
      tileT[(fc*4+3)*68 + row] = f2bf_s(v.w);
    }
    __syncthreads();
    u16x8 o = *(const u16x8*)(tileT + cc*68 + sg*8);
    *(u16x8*)((unsigned short*)outp + (size_t)(c0+cc)*R + r0 + sg*8) = o;
  }
}

__global__ __launch_bounds__(256) void k_prep(
    const float* __restrict__ Wxz, const float* __restrict__ Wout,
    const float* __restrict__ Wx, const float* __restrict__ Wdt,
    const float* __restrict__ lmw,
    bf16* wxz_bf, bf16* wout_bf, bf16* wx_bf, bf16* wdt_bf, bf16* lm_bf){
  __shared__ __align__(16) short tileT[32*68];
  int gdim = gridDim.x;
  t_job(Wxz,  wxz_bf,  DM_, E2,  NLAY, tileT, gdim);
  t_job(Wout, wout_bf, EE,  DM_, NLAY, tileT, gdim);
  t_job(Wx,   wx_bf,   EE,  NXD, NLAY, tileT, gdim);
  t_job(Wdt,  wdt_bf,  RNK, EE,  NLAY, tileT, gdim);
  t_job(lmw,  lm_bf,   DM_, VOC, 1,    tileT, gdim);
}

// ---------------- fused: h = (embed | h+s0+s1); rmsnorm -> bf16; optional zero xdbl / d_out ----------------
__global__ void k_rmsnorm_fuse(const int* __restrict__ ids, const float* __restrict__ emb,
                               float* __restrict__ h, const float* __restrict__ s0,
                               const float* __restrict__ s1, const float* __restrict__ w,
                               bf16* __restrict__ u, float* __restrict__ xdz,
                               float* __restrict__ zout){
  int t = blockIdx.x;
  float* hp = h + (size_t)t*DM_;
  float v[4];
  float ss = 0.f;
#pragma unroll
  for (int j = 0; j < 4; j++){
    int i = threadIdx.x + j*256;
    float x;
    if (ids){ x = emb[(size_t)ids[t]*DM_ + i]; hp[i] = x; }
    else { x = hp[i] + s0[(size_t)t*DM_ + i] + s1[(size_t)t*DM_ + i]; hp[i] = x; }
    v[j] = x; ss += x*x;
  }
#pragma unroll
  for (int o = 32; o > 0; o >>= 1) ss += __shfl_down(ss, o, 64);
  __shared__ float red[4];
  if ((threadIdx.x & 63) == 0) red[threadIdx.x >> 6] = ss;
  __syncthreads();
  float tot = red[0]+red[1]+red[2]+red[3];
  float sc = rsqrtf(tot*(1.f/DM_) + EPS_);
  bf16* up = u + (size_t)t*DM_;
#pragma unroll
  for (int j = 0; j < 4; j++){
    int i = threadIdx.x + j*256;
    up[i] = __float2bfloat16(v[j]*sc*w[i]);
  }
  if (xdz && threadIdx.x < NXD) xdz[(size_t)t*NXD + threadIdx.x] = 0.f;
  if (zout) zout[(size_t)t*VOC + threadIdx.x] = 0.f;
}

// ---------------- bf16 MFMA GEMM, dbuf LDS via global_load_lds, XOR-swizzled ----------------
// MODE 0: C=acc   4: slab write C[z*M*N+idx]=acc   5: atomicAdd(C,acc)
template<int BM, int BN, int NWM, int NWN, int MODE>
__global__ __launch_bounds__(256) void k_gemm(
    const short* __restrict__ A, const short* __restrict__ Bt, float* __restrict__ C,
    int M, int N, int K, int Ksplit)
{
  constexpr int BK = 64;
  constexpr int WM = BM/NWM, WN = BN/NWN;
  constexpr int MT = WM/16, NT = WN/16;
  constexpr int ABY = BM*BK*2, BBY = BN*BK*2;
  constexpr int AISS = ABY/4096, BISS = BBY/4096;
  __shared__ __align__(16) short As[2][BM*BK];
  __shared__ __align__(16) short Bs[2][BN*BK];
  int tid = threadIdx.x, lane = tid & 63, wave = tid >> 6;
  int wr = wave / NWN, wc = wave % NWN;
  int m0 = blockIdx.x * BM, n0 = blockIdx.y * BN;
  int lrow = lane & 15, lq = lane >> 4;
  int wbase = (tid & ~63) * 16;

  int kbeg = blockIdx.z * Ksplit;
  int nk = Ksplit / BK;

  f32x4 acc[MT][NT];
#pragma unroll
  for (int i = 0; i < MT; i++)
#pragma unroll
    for (int j = 0; j < NT; j++) acc[i][j] = (f32x4){0.f,0.f,0.f,0.f};

  auto stage = [&](int k0, int buf){
#pragma unroll
    for (int i = 0; i < AISS; i++){
      int off = i*4096 + tid*16;
      int row = off >> 7;
      int kc  = ((off >> 4) & 7) ^ (row & 7);
      gld_lds16(A + (size_t)(m0+row)*K + k0 + kc*8, As[buf] + ((i*4096 + wbase) >> 1));
    }
#pragma unroll
    for (int i = 0; i < BISS; i++){
      int off = i*4096 + tid*16;
      int row = off >> 7;
      int kc  = ((off >> 4) & 7) ^ (row & 7);
      gld_lds16(Bt + (size_t)(n0+row)*K + k0 + kc*8, Bs[buf] + ((i*4096 + wbase) >> 1));
    }
  };

  stage(kbeg, 0);
  __syncthreads();
  for (int it = 0; it < nk; it++){
    int cur = it & 1;
    if (it + 1 < nk) stage(kbeg + (it+1)*BK, cur ^ 1);
#pragma unroll
    for (int s = 0; s < 2; s++){
      bf16x8 af[MT], bfr[NT];
#pragma unroll
      for (int mt = 0; mt < MT; mt++){
        int row = wr*WM + mt*16 + lrow;
        int cc = (s*4 + lq) ^ (row & 7);
        af[mt] = *(const bf16x8*)(As[cur] + row*BK + cc*8);
      }
#pragma unroll
      for (int nt = 0; nt < NT; nt++){
        int row = wc*WN + nt*16 + lrow;
        int cc = (s*4 + lq) ^ (row & 7);
        bfr[nt] = *(const bf16x8*)(Bs[cur] + row*BK + cc*8);
      }
#pragma unroll
      for (int mt = 0; mt < MT; mt++)
#pragma unroll
        for (int nt = 0; nt < NT; nt++)
          acc[mt][nt] = __builtin_amdgcn_mfma_f32_16x16x32_bf16(af[mt], bfr[nt], acc[mt][nt], 0,0,0);
    }
    __syncthreads();
  }

  size_t slab = (MODE == 4) ? (size_t)blockIdx.z * M * N : 0;
#pragma unroll
  for (int mt = 0; mt < MT; mt++){
    int row = m0 + wr*WM + mt*16 + lq*4;
#pragma unroll
    for (int nt = 0; nt < NT; nt++){
      int col = n0 + wc*WN + nt*16 + lrow;
#pragma unroll
      for (int r = 0; r < 4; r++){
        float v = acc[mt][nt][r];
        size_t idx = slab + (size_t)(row + r)*N + col;
        if (MODE == 5) atomicAdd(&C[idx], v);
        else C[idx] = v;
      }
    }
  }
}

// ---------------- fused conv+silu + Wx GEMM (split-16 K, atomic into xdbl) ----------------
// grid (SEQ/32, 1, 16). A-tile (32t x 64e) computed from xzb via conv in registers,
// written to xact (f32) and packed bf16 into swizzled LDS. B staged via gld_lds.
__global__ __launch_bounds__(256) void k_wx_conv(
    const float* __restrict__ xzb, const float* __restrict__ cw, const float* __restrict__ cb,
    const short* __restrict__ WxT, float* __restrict__ xact, float* __restrict__ xdbl)
{
  __shared__ __align__(16) short As[2][32*64];
  __shared__ __align__(16) short Bs[2][96*64];
  int tid = threadIdx.x, lane = tid & 63, wave = tid >> 6;
  int wr = wave >> 1, wc = wave & 1;
  int lrow = lane & 15, lq = lane >> 4;
  int wbase = (tid & ~63) * 16;
  int m0 = blockIdx.x * 32;
  int kbeg = blockIdx.z * 128;

  int arow = tid >> 3;     // t-local 0..31
  int ag   = tid & 7;      // e-octet 0..7
  int t    = m0 + arow;

  auto stageA = [&](int k0, int buf){
    int e0 = k0 + ag*8;
    float v[8];
#pragma unroll
    for (int j = 0; j < 8; j++){
      int e = e0 + j;
      float4 w4 = *(const float4*)(cw + (size_t)e*4);
      float a = cb[e];
      if (t >= 3){
        a += xzb[(size_t)(t-3)*E2 + e]*w4.x + xzb[(size_t)(t-2)*E2 + e]*w4.y
           + xzb[(size_t)(t-1)*E2 + e]*w4.z + xzb[(size_t)t*E2 + e]*w4.w;
      } else {
        const float* wp = (const float*)&w4;
#pragma unroll
        for (int k = 0; k < 4; k++){ int tt = t-3+k; if (tt >= 0) a += xzb[(size_t)tt*E2 + e]*wp[k]; }
      }
      v[j] = a * sigmoidf_(a);
    }
    float4 v0 = {v[0],v[1],v[2],v[3]}, v1 = {v[4],v[5],v[6],v[7]};
    *(float4*)(xact + (size_t)t*EE + e0)     = v0;
    *(float4*)(xact + (size_t)t*EE + e0 + 4) = v1;
    short tmp[8] __attribute__((aligned(16)));
#pragma unroll
    for (int j = 0; j < 8; j++) tmp[j] = f2bf_s(v[j]);
    int c = ag ^ (arow & 7);
    *(bf16x8*)(As[buf] + arow*64 + c*8) = *(const bf16x8*)tmp;
  };
  auto stageB = [&](int k0, int buf){
#pragma unroll
    for (int i = 0; i < 3; i++){
      int off = i*4096 + tid*16;
      int row = off >> 7;
      int kc  = ((off >> 4) & 7) ^ (row & 7);
      gld_lds16(WxT + (size_t)row*EE + k0 + kc*8, Bs[buf] + ((i*4096 + wbase) >> 1));
    }
  };

  stageA(kbeg, 0); stageB(kbeg, 0);
  __syncthreads();
  f32x4 acc[3];
#pragma unroll
  for (int j = 0; j < 3; j++) acc[j] = (f32x4){0.f,0.f,0.f,0.f};
  for (int it = 0; it < 2; it++){
    int cur = it & 1;
    if (it == 0){ stageA(kbeg + 64, 1); stageB(kbeg + 64, 1); }
#pragma unroll
    for (int s = 0; s < 2; s++){
      int rowa = wr*16 + lrow;
      int cca = (s*4 + lq) ^ (rowa & 7);
      bf16x8 af = *(const bf16x8*)(As[cur] + rowa*64 + cca*8);
#pragma unroll
      for (int nt = 0; nt < 3; nt++){
        int rowb = wc*48 + nt*16 + lrow;
        int ccb = (s*4 + lq) ^ (rowb & 7);
        bf16x8 bfr = *(const bf16x8*)(Bs[cur] + rowb*64 + ccb*8);
        acc[nt] = __builtin_amdgcn_mfma_f32_16x16x32_bf16(af, bfr, acc[nt], 0,0,0);
      }
    }
    __syncthreads();
  }
  int rowg = m0 + wr*16 + lq*4;
#pragma unroll
  for (int nt = 0; nt < 3; nt++){
    int col = wc*48 + nt*16 + lrow;
#pragma unroll
    for (int r = 0; r < 4; r++)
      atomicAdd(&xdbl[(size_t)(rowg+r)*NXD + col], acc[nt][r]);
  }
}

// ---------------- fused dt GEMM (A cast in-staging) + scanA epilogue ----------------
__global__ __launch_bounds__(256) void k_dt_scanA(
    const float* __restrict__ xdbl, const short* __restrict__ WdtT,
    const float* __restrict__ dtb, const float* __restrict__ Alog,
    const float* __restrict__ xact, float* __restrict__ dtbuf,
    float* __restrict__ S, float* __restrict__ dtsum)
{
  __shared__ __align__(16) char smem[22528];
  short* As = (short*)smem;            // 8K
  short* Bs = (short*)(smem + 8192);   // 8K
  float (*dts)[65]  = (float(*)[65])smem;            // 64x65 f32 (reuse)
  float (*Bcol)[17] = (float(*)[17])(smem + 16640);  // 64x17 f32
  int tid = threadIdx.x;
  int lane = tid & 63, wave = tid >> 6;
  int wr = wave >> 1, wc = wave & 1, lrow = lane & 15, lq = lane >> 4;
  int m0 = blockIdx.x*64, n0 = blockIdx.y*64;

  {
    int row = tid >> 2;
    int kq  = (tid & 3) << 4;
    const float* src = xdbl + (size_t)(m0+row)*NXD + kq;
    short tmp[16] __attribute__((aligned(16)));
#pragma unroll
    for (int j = 0; j < 16; j++) tmp[j] = f2bf_s(src[j]);
    int c0 = ((kq>>3) + 0) ^ (row & 7);
    int c1 = ((kq>>3) + 1) ^ (row & 7);
    *(bf16x8*)(As + row*64 + c0*8) = *(const bf16x8*)(tmp);
    *(bf16x8*)(As + row*64 + c1*8) = *(const bf16x8*)(tmp + 8);
  }
  {
    int wbase = (tid & ~63) * 16;
#pragma unroll
    for (int i = 0; i < 2; i++){
      int off = i*4096 + tid*16;
      int row = off >> 7;
      int kc  = ((off >> 4) & 7) ^ (row & 7);
      gld_lds16(WdtT + (size_t)(n0+row)*RNK + kc*8, Bs + ((i*4096 + wbase) >> 1));
    }
  }
  __syncthreads();
  f32x4 acc[2][2];
#pragma unroll
  for (int i = 0; i < 2; i++)
#pragma unroll
    for (int j = 0; j < 2; j++) acc[i][j] = (f32x4){0.f,0.f,0.f,0.f};
#pragma unroll
  for (int s = 0; s < 2; s++){
    bf16x8 af[2], bfr[2];
#pragma unroll
    for (int mt = 0; mt < 2; mt++){
      int row = wr*32 + mt*16 + lrow;
      int cc = (s*4 + lq) ^ (row & 7);
      af[mt] = *(const bf16x8*)(As + row*64 + cc*8);
    }
#pragma unroll
    for (int nt = 0; nt < 2; nt++){
      int row = wc*32 + nt*16 + lrow;
      int cc = (s*4 + lq) ^ (row & 7);
      bfr[nt] = *(const bf16x8*)(Bs + row*64 + cc*8);
    }
#pragma unroll
    for (int mt = 0; mt < 2; mt++)
#pragma unroll
      for (int nt = 0; nt < 2; nt++)
        acc[mt][nt] = __builtin_amdgcn_mfma_f32_16x16x32_bf16(af[mt], bfr[nt], acc[mt][nt], 0,0,0);
  }
  __syncthreads();

#pragma unroll
  for (int mt = 0; mt < 2; mt++){
    int rl = wr*32 + mt*16 + lq*4;
#pragma unroll
    for (int nt = 0; nt < 2; nt++){
      int cl = wc*32 + nt*16 + lrow;
#pragma unroll
      for (int r = 0; r < 4; r++){
        float v = softplusf_(acc[mt][nt][r] + dtb[n0 + cl]);
        dtbuf[(size_t)(m0 + rl + r)*EE + n0 + cl] = v;
        dts[rl + r][cl] = v;
      }
    }
  }
  {
    int row = tid >> 2, n4 = (tid & 3) << 2;
    float4 b4 = *(const float4*)(xdbl + (size_t)(m0+row)*NXD + RNK + n4);
    Bcol[row][n4+0] = b4.x; Bcol[row][n4+1] = b4.y;
    Bcol[row][n4+2] = b4.z; Bcol[row][n4+3] = b4.w;
  }
  __syncthreads();

  if (tid < 128){
    int ch = tid >> 6, el = tid & 63;
    int e = n0 + el;
    int c = (m0 >> 5) + ch;
    int t0 = c*CLEN;
    const float* Al = Alog + (size_t)e*NST;
    float Ae[NST];
#pragma unroll
    for (int n = 0; n < NST; n++) Ae[n] = -__expf(Al[n]);
    float h[NST];
#pragma unroll
    for (int n = 0; n < NST; n++) h[n] = 0.f;
    float ds = 0.f;
    for (int tt = 0; tt < CLEN; tt++){
      float dtv = dts[ch*CLEN + tt][el];
      float xv  = xact[(size_t)(t0+tt)*EE + e];
      ds += dtv;
      float sx = dtv*xv;
#pragma unroll
      for (int n = 0; n < NST; n++)
        h[n] = __expf(dtv*Ae[n])*h[n] + sx*Bcol[ch*CLEN + tt][n];
    }
    float* Sp = S + ((size_t)c*EE + e)*NST;
#pragma unroll
    for (int n = 0; n < NST; n++) Sp[n] = h[n];
    dtsum[(size_t)c*EE + e] = ds;
  }
}

// ---------------- scanC: inline chunk prefix + recompute + gate ----------------
__global__ void k_scanC(const float* __restrict__ dt, const float* __restrict__ x,
                        const float* __restrict__ xdbl, const float* __restrict__ Alog,
                        const float* __restrict__ Dp, const float* __restrict__ S,
                        const float* __restrict__ dtsum, const float* __restrict__ xz,
                        bf16* __restrict__ ybf){
  int e = blockIdx.x*256 + threadIdx.x;
  int c = blockIdx.y;
  int t0 = c*CLEN;
  float Ae[NST];
#pragma unroll
  for (int n = 0; n < NST; n++) Ae[n] = -__expf(Alog[(size_t)e*NST + n]);
  __shared__ float Bsm[CLEN][NST], Csm[CLEN][NST];
  for (int i = threadIdx.x; i < CLEN*NST; i += 256){
    int tt = i>>4, n = i&15;
    Bsm[tt][n] = xdbl[(size_t)(t0+tt)*NXD + RNK + n];
    Csm[tt][n] = xdbl[(size_t)(t0+tt)*NXD + RNK + NST + n];
  }
  __syncthreads();
  float h[NST];
#pragma unroll
  for (int n = 0; n < NST; n++) h[n] = 0.f;
  for (int j = 0; j < c; j++){
    float dsj = dtsum[(size_t)j*EE + e];
    const float* Sj = S + ((size_t)j*EE + e)*NST;
#pragma unroll
    for (int n = 0; n < NST; n++)
      h[n] = __expf(dsj*Ae[n])*h[n] + Sj[n];
  }
  float Dv = Dp[e];
  for (int tt = 0; tt < CLEN; tt++){
    float dtv = dt[(size_t)(t0+tt)*EE + e];
    float xv  = x[(size_t)(t0+tt)*EE + e];
    float sx = dtv*xv;
    float y = Dv*xv;
#pragma unroll
    for (int n = 0; n < NST; n++){
      h[n] = __expf(dtv*Ae[n])*h[n] + sx*Bsm[tt][n];
      y += h[n]*Csm[tt][n];
    }
    float zv = xz[(size_t)(t0+tt)*E2 + EE + e];
    y *= zv*sigmoidf_(zv);
    ybf[(size_t)(t0+tt)*EE + e] = __float2bfloat16(y);
  }
}

// ---------------- launch ----------------
extern "C" void kernel_launch(void* const* d_in, const int* in_sizes, int n_in,
                              void* d_out, int out_size, void* d_ws, size_t ws_size,
                              hipStream_t stream)
{
  const int*   ids  = (const int*)d_in[0];
  const float* emb  = (const float*)d_in[1];
  const float* Wxz  = (const float*)d_in[2];
  const float* cw   = (const float*)d_in[3];
  const float* cb   = (const float*)d_in[4];
  const float* Wx   = (const float*)d_in[5];
  const float* Wdt  = (const float*)d_in[6];
  const float* dtb  = (const float*)d_in[7];
  const float* Alog = (const float*)d_in[8];
  const float* Dp   = (const float*)d_in[9];
  const float* Wout = (const float*)d_in[10];
  const float* nw   = (const float*)d_in[11];
  const float* fnw  = (const float*)d_in[12];
  const float* lmw  = (const float*)d_in[13];

  char* p = (char*)d_ws;
  auto alloc = [&](size_t bytes){ void* r = (void*)p; p += (bytes + 255) & ~(size_t)255; return r; };
  bf16* wxz_bf  = (bf16*)alloc((size_t)NLAY*E2*DM_*2);
  bf16* wout_bf = (bf16*)alloc((size_t)NLAY*DM_*EE*2);
  bf16* wx_bf   = (bf16*)alloc((size_t)NLAY*NXD*EE*2);
  bf16* wdt_bf  = (bf16*)alloc((size_t)NLAY*EE*RNK*2);
  bf16* lm_bf   = (bf16*)alloc((size_t)VOC*DM_*2);
  float* h      = (float*)alloc((size_t)SEQ*DM_*4);
  float* hslab  = (float*)alloc((size_t)2*SEQ*DM_*4);
  bf16* u_bf    = (bf16*)alloc((size_t)SEQ*DM_*2);
  float* xzb    = (float*)alloc((size_t)SEQ*E2*4);
  float* xact   = (float*)alloc((size_t)SEQ*EE*4);
  float* xdbl   = (float*)alloc((size_t)SEQ*NXD*4);
  float* dtbuf  = (float*)alloc((size_t)SEQ*EE*4);
  float* Sbuf   = (float*)alloc((size_t)NCH*EE*NST*4);
  float* dtsum  = (float*)alloc((size_t)NCH*EE*4);
  bf16* y_bf    = (bf16*)alloc((size_t)SEQ*EE*2);

  k_prep<<<2048, 256, 0, stream>>>(Wxz, Wout, Wx, Wdt, lmw,
                                   wxz_bf, wout_bf, wx_bf, wdt_bf, lm_bf);

  for (int l = 0; l < NLAY; l++){
    k_rmsnorm_fuse<<<SEQ, 256, 0, stream>>>(
        l == 0 ? ids : nullptr, emb, h,
        hslab, hslab + (size_t)SEQ*DM_,
        nw + (size_t)l*DM_, u_bf, xdbl, nullptr);
    k_gemm<128,64,2,2,0><<<dim3(SEQ/128, E2/64, 1), 256, 0, stream>>>(
        (const short*)u_bf, (const short*)(wxz_bf + (size_t)l*E2*DM_), xzb,
        SEQ, E2, DM_, DM_);
    k_wx_conv<<<dim3(SEQ/32, 1, 16), 256, 0, stream>>>(
        xzb, cw + (size_t)l*EE*4, cb + (size_t)l*EE,
        (const short*)(wx_bf + (size_t)l*NXD*EE), xact, xdbl);
    k_dt_scanA<<<dim3(SEQ/64, EE/64), 256, 0, stream>>>(
        xdbl, (const short*)(wdt_bf + (size_t)l*EE*RNK), dtb + (size_t)l*EE,
        Alog + (size_t)l*EE*NST, xact, dtbuf, Sbuf, dtsum);
    k_scanC<<<dim3(EE/256, NCH), 256, 0, stream>>>(
        dtbuf, xact, xdbl, Alog + (size_t)l*EE*NST, Dp + (size_t)l*EE,
        Sbuf, dtsum, xzb, y_bf);
    k_gemm<64,64,2,2,4><<<dim3(SEQ/64, DM_/64, 2), 256, 0, stream>>>(
        (const short*)y_bf, (const short*)(wout_bf + (size_t)l*DM_*EE), hslab,
        SEQ, DM_, EE, EE/2);
  }
  k_rmsnorm_fuse<<<SEQ, 256, 0, stream>>>(
      nullptr, emb, h, hslab, hslab + (size_t)SEQ*DM_, fnw, u_bf, nullptr, (float*)d_out);
  k_gemm<64,64,2,2,5><<<dim3(SEQ/64, VOC/64, 4), 256, 0, stream>>>(
      (const short*)u_bf, (const short*)lm_bf, (float*)d_out,
      SEQ, VOC, DM_, DM_/4);
}